// Round 11
// baseline (805.578 us; speedup 1.0000x reference)
//
#include <hip/hip_runtime.h>

typedef float f4 __attribute__((ext_vector_type(4)));

#define Nn 256
#define Mm 512
#define Dd 64
#define EPSF 1e-6f
#define INFF 1e30f
#define BC 16              // chunk width (columns per systolic step)
#define NCHUNK (Nn / BC)   // 16
#define R 16               // rows per wave-stage
#define NBLK 8             // pipeline groups (blocks)
#define WVS 4              // waves per block (256 threads, 1 wave/SIMD)
#define SST (NBLK * WVS)   // 32 stages total
#define SLOTS 4            // LDS slice ring depth

// workspace layout (float offsets)
#define OFF_D     0                    // d[m][n]        512*256
#define OFF_QC    131072               // qc[nb][j]=q[j][nb]  256*257
#define OFF_P     (OFF_QC + 65792)     // p[257]
#define OFF_WT    (OFF_P + 260)        // wT[t][n]=w[n][t]    256*256
#define OFF_WS    (OFF_WT + 65536)     // W[n] column sums    256
#define OFF_CBAR  (OFF_WS + 256)       // inter-block Cbar slices 256*256
#define OFF_CROW  (OFF_CBAR + 65536)   // C row handoffs (region sized SST*Nn)
#define OFF_FLAG  (OFF_CROW + SST*Nn)  // flags[blk][chunk], NBLK*NCHUNK ints

// ---------------- LLC-coherent (sc0 sc1) helpers — proven round-2 forms, widened ----------------
__device__ __forceinline__ int llc_load_int(const int* p) {
  int v;
  asm volatile("global_load_dword %0, %1, off sc0 sc1\n\ts_waitcnt vmcnt(0)"
               : "=v"(v) : "v"(p) : "memory");
  return v;
}
__device__ __forceinline__ void llc_store_int(int* p, int v) {
  asm volatile("global_store_dword %0, %1, off sc0 sc1" :: "v"(p), "v"(v) : "memory");
}
// blocking: 16 cbar rows + 4 crow vectors in one round trip (ends drained — registers
// are complete at asm exit; the proven-safe blocking pattern)
__device__ __forceinline__ void llc_load_cbar20(const float* b0, const float* cp,
                                                f4 c[16], f4 cr[4]) {
  const float* b1 = b0 + 4 * Nn;
  const float* b2 = b0 + 8 * Nn;
  const float* b3 = b0 + 12 * Nn;
  asm volatile(
    "global_load_dwordx4 %0, %20, off sc0 sc1\n\t"
    "global_load_dwordx4 %1, %20, off offset:1024 sc0 sc1\n\t"
    "global_load_dwordx4 %2, %20, off offset:2048 sc0 sc1\n\t"
    "global_load_dwordx4 %3, %20, off offset:3072 sc0 sc1\n\t"
    "global_load_dwordx4 %4, %21, off sc0 sc1\n\t"
    "global_load_dwordx4 %5, %21, off offset:1024 sc0 sc1\n\t"
    "global_load_dwordx4 %6, %21, off offset:2048 sc0 sc1\n\t"
    "global_load_dwordx4 %7, %21, off offset:3072 sc0 sc1\n\t"
    "global_load_dwordx4 %8, %22, off sc0 sc1\n\t"
    "global_load_dwordx4 %9, %22, off offset:1024 sc0 sc1\n\t"
    "global_load_dwordx4 %10, %22, off offset:2048 sc0 sc1\n\t"
    "global_load_dwordx4 %11, %22, off offset:3072 sc0 sc1\n\t"
    "global_load_dwordx4 %12, %23, off sc0 sc1\n\t"
    "global_load_dwordx4 %13, %23, off offset:1024 sc0 sc1\n\t"
    "global_load_dwordx4 %14, %23, off offset:2048 sc0 sc1\n\t"
    "global_load_dwordx4 %15, %23, off offset:3072 sc0 sc1\n\t"
    "global_load_dwordx4 %16, %24, off sc0 sc1\n\t"
    "global_load_dwordx4 %17, %24, off offset:16 sc0 sc1\n\t"
    "global_load_dwordx4 %18, %24, off offset:32 sc0 sc1\n\t"
    "global_load_dwordx4 %19, %24, off offset:48 sc0 sc1\n\t"
    "s_waitcnt vmcnt(0)"
    : "=v"(c[0]), "=v"(c[1]), "=v"(c[2]), "=v"(c[3]),
      "=v"(c[4]), "=v"(c[5]), "=v"(c[6]), "=v"(c[7]),
      "=v"(c[8]), "=v"(c[9]), "=v"(c[10]), "=v"(c[11]),
      "=v"(c[12]), "=v"(c[13]), "=v"(c[14]), "=v"(c[15]),
      "=v"(cr[0]), "=v"(cr[1]), "=v"(cr[2]), "=v"(cr[3])
    : "v"(b0), "v"(b1), "v"(b2), "v"(b3), "v"(cp)
    : "memory");
}
__device__ __forceinline__ void llc_store_cbar16(float* b0, const f4 c[16]) {
  float* b1 = b0 + 4 * Nn;
  float* b2 = b0 + 8 * Nn;
  float* b3 = b0 + 12 * Nn;
  asm volatile(
    "global_store_dwordx4 %16, %0, off sc0 sc1\n\t"
    "global_store_dwordx4 %16, %1, off offset:1024 sc0 sc1\n\t"
    "global_store_dwordx4 %16, %2, off offset:2048 sc0 sc1\n\t"
    "global_store_dwordx4 %16, %3, off offset:3072 sc0 sc1\n\t"
    "global_store_dwordx4 %17, %4, off sc0 sc1\n\t"
    "global_store_dwordx4 %17, %5, off offset:1024 sc0 sc1\n\t"
    "global_store_dwordx4 %17, %6, off offset:2048 sc0 sc1\n\t"
    "global_store_dwordx4 %17, %7, off offset:3072 sc0 sc1\n\t"
    "global_store_dwordx4 %18, %8, off sc0 sc1\n\t"
    "global_store_dwordx4 %18, %9, off offset:1024 sc0 sc1\n\t"
    "global_store_dwordx4 %18, %10, off offset:2048 sc0 sc1\n\t"
    "global_store_dwordx4 %18, %11, off offset:3072 sc0 sc1\n\t"
    "global_store_dwordx4 %19, %12, off sc0 sc1\n\t"
    "global_store_dwordx4 %19, %13, off offset:1024 sc0 sc1\n\t"
    "global_store_dwordx4 %19, %14, off offset:2048 sc0 sc1\n\t"
    "global_store_dwordx4 %19, %15, off offset:3072 sc0 sc1\n\t"
    "s_waitcnt vmcnt(0)"
    :: "v"(c[0]), "v"(c[1]), "v"(c[2]), "v"(c[3]),
       "v"(c[4]), "v"(c[5]), "v"(c[6]), "v"(c[7]),
       "v"(c[8]), "v"(c[9]), "v"(c[10]), "v"(c[11]),
       "v"(c[12]), "v"(c[13]), "v"(c[14]), "v"(c[15]),
       "v"(b0), "v"(b1), "v"(b2), "v"(b3)
    : "memory");
}
__device__ __forceinline__ float rdlane(float v, int l) {
  return __int_as_float(__builtin_amdgcn_readlane(__float_as_int(v), l));
}

// ---------------- fused setup: dist (b<512) | qt (b<769) | init (b==769) ----------------
__global__ __launch_bounds__(256) void k_pre(const float* __restrict__ x,
                                             const float* __restrict__ y,
                                             const float* __restrict__ q,
                                             float* __restrict__ ws) {
  const int b = blockIdx.x, t = threadIdx.x;
  if (b < Mm) {
    __shared__ float xs[Dd];
    if (t < Dd) xs[t] = x[b * Dd + t];
    __syncthreads();
    const float4* y4 = (const float4*)(y + t * Dd);
    float acc = 0.f;
#pragma unroll
    for (int k = 0; k < Dd / 4; k++) {
      float4 v = y4[k];
      float a0 = xs[4*k+0] - v.x, a1 = xs[4*k+1] - v.y;
      float a2 = xs[4*k+2] - v.z, a3 = xs[4*k+3] - v.w;
      acc += a0*a0 + a1*a1 + a2*a2 + a3*a3;
    }
    ws[OFF_D + b * Nn + t] = sqrtf(acc);
  } else if (b < Mm + 257) {
    const int j = b - Mm;                 // qc[nb][j] = q[j][nb]
    ws[OFF_QC + t * 257 + j] = q[j * Nn + t];
  } else {
    ws[OFF_WS + t] = 0.f;
    if (t < NBLK * NCHUNK) ((int*)(ws + OFF_FLAG))[t] = 0;
  }
}

__global__ __launch_bounds__(256) void k_reach(const float* __restrict__ qc, float* __restrict__ p_out) {
  __shared__ float p[257];
  __shared__ float vsnap[64];
  __shared__ float qtile[64][65];
  int tid = threadIdx.x;
  p[tid] = (tid == 0) ? 1.f : 0.f;
  if (tid == 0) p[256] = 0.f;
  __syncthreads();
  for (int g = 0; g < 4; g++) {
    int g0 = g * 64;
    for (int z = 0; z < 16; z++) {
      int idx = tid + z * 256, k = idx >> 6, l = idx & 63;
      qtile[k][l] = qc[(g0 + k) * 257 + g0 + l];
    }
    __syncthreads();
    if (tid < 64) {
      float pv = p[g0 + tid];
      for (int k = 0; k < 64; k++) {
        float v = __shfl(pv, k, 64);
        if (tid == k) vsnap[k] = v;
        pv += v * qtile[k][tid];
      }
    }
    __syncthreads();
    float acc = p[tid];
    float acc2 = (tid == 0) ? p[256] : 0.f;
    for (int k = 0; k < 64; k++) {
      float v = vsnap[k];
      acc += v * qc[(g0 + k) * 257 + tid];
      if (tid == 0) acc2 += v * qc[(g0 + k) * 257 + 256];
    }
    __syncthreads();
    p[tid] = acc;
    if (tid == 0) p[256] = acc2;
    __syncthreads();
  }
  p_out[tid] = p[tid];
  if (tid == 0) p_out[256] = p[256];
}

__global__ __launch_bounds__(256) void k_wbuild(const float* __restrict__ qc, const float* __restrict__ p,
                                                float* __restrict__ wT, float* __restrict__ Wsum) {
  int t = blockIdx.x, n = threadIdx.x;
  float v = 0.f;
  if (t < n) v = p[t] * qc[t * 257 + n] / (p[n] + EPSF);
  wT[t * Nn + n] = v;
  if (v != 0.f) atomicAdd(&Wsum[n], v);
}

// ---------------- main systolic DP: 8 blocks x 4 waves, BC=16 (fat steps) ----------------
// Round-2 protocol byte-equivalent (blocking in-step poll + payload in wave 0; store+drain+
// publish in wave 3). ONLY change: chunk width 8 -> 16, halving the diagonal (63 -> 47
// stage-steps) while per-step fixed overhead (1 poll RTT + 1 payload RTT + 1 store drain)
// stays constant. Owner lanes per chunk: 4j..4j+3; owner = 4j + (tt>>2), comp = tt&3.
__global__ __launch_bounds__(256, 1) void k_main(const float* __restrict__ d,
                                                 const float* __restrict__ wT,
                                                 const float* __restrict__ Wsum,
                                                 float* __restrict__ cbarG,
                                                 float* __restrict__ crowG,
                                                 int* __restrict__ flags,
                                                 const float* __restrict__ q,
                                                 const float* __restrict__ p,
                                                 float* __restrict__ out) {
  __shared__ __align__(16) float sbuf[SLOTS][BC * Nn];       // 64 KB slice ring
  __shared__ __align__(16) float crow_lds[WVS][SLOTS][BC];   // 1 KB crow handoffs
  __shared__ __align__(16) float crow_fin[Nn];               // last block: C_last stash

  const int tid  = threadIdx.x;
  const int wave = tid >> 6;         // 0..3: stage within block
  const int lane = tid & 63;         // owns columns 4*lane .. 4*lane+3
  const int blk  = blockIdx.x;
  const int stage = blk * WVS + wave;
  const int m0 = stage * R;

  f4 dl[R], S[R];
#pragma unroll
  for (int r = 0; r < R; r++) {
    dl[r] = *(const f4*)(d + (m0 + r) * Nn + 4 * lane);
    S[r] = (f4){0.f, 0.f, 0.f, 0.f};
  }
  f4 Wt = *(const f4*)(Wsum + 4 * lane);

#pragma clang loop unroll(disable)
  for (int s = 0; s < NCHUNK + WVS - 1; s++) {
    const int j = s - wave;
    if (j >= 0 && j < NCHUNK) {
      // wT chunk: plain cached loads (read-only, L2-resident) — issue before any wait
      f4 wv[BC];
#pragma unroll
      for (int tt = 0; tt < BC; tt++)
        wv[tt] = *(const f4*)(wT + (j * BC + tt) * Nn + 4 * lane);

      f4 c[BC], cr4[4];
      float* lsl = &sbuf[j & (SLOTS - 1)][0] + 4 * lane;

      if (wave == 0) {
        if (blk > 0) {
          const int* fp = flags + (blk - 1) * NCHUNK + j;
          while (llc_load_int(fp) == 0) __builtin_amdgcn_s_sleep(1);
          llc_load_cbar20(cbarG + (size_t)j * BC * Nn + 4 * lane,
                          crowG + (blk - 1) * Nn + j * BC, c, cr4);
        } else {
          cr4[0] = (f4){INFF, INFF, INFF, INFF};
          cr4[1] = cr4[0]; cr4[2] = cr4[0]; cr4[3] = cr4[0];
#pragma unroll
          for (int tt = 0; tt < BC; tt++) c[tt] = cr4[0];
        }
      } else {
        // slice written by wave-1 at step s-1 (barrier-separated)
#pragma unroll
        for (int tt = 0; tt < BC; tt++) c[tt] = *(const f4*)(lsl + tt * Nn);
        const float* cr = &crow_lds[wave - 1][j & (SLOTS - 1)][0];
#pragma unroll
        for (int i = 0; i < 4; i++) cr4[i] = *(const f4*)(cr + 4 * i);
      }

      f4 clast4;
      const bool isJ0 = (j == 0);
#pragma unroll
      for (int tt = 0; tt < BC; tt++) {
        const int owner = 4 * j + (tt >> 2);   // wave-uniform
        const int comp = tt & 3;               // == t & 3 (compile-time)
        const bool isT0 = isJ0 && (tt == 0);

        float up = cr4[tt >> 2][comp];          // upstream C[m0-1][t]
        float prcMin = up;                      // for cmin2
        float prcVal = up;                      // for the t==0 value chain
        if (isT0 && stage == 0) prcVal = 0.f;
        float cml[R];
#pragma unroll
        for (int r = 0; r < R; r++) {
          float Cv;
          if (isT0) Cv = dl[r][0] + prcVal;                       // C[m][0] = d + C[m-1][0]
          else      Cv = fmaf(dl[r][comp], Wt[comp], S[r][comp]); // C[m][t] = d*W + S
          cml[r] = fminf(Cv, prcMin);                             // cmin2 = min(C[m][t], C[m-1][t])
          prcVal = Cv;
          prcMin = Cv;
        }
        // broadcast owner lane's cmin2 chain + last-row C to all lanes
        float cmB[R];
#pragma unroll
        for (int r = 0; r < R; r++) cmB[r] = rdlane(cml[r], owner);
        float clastv = rdlane(prcVal, owner);
        if (lane == owner) clast4[comp] = clastv;

        // stream update: for each owned column n, chain Cbar through 16 rows
#pragma unroll
        for (int k = 0; k < 4; k++) {
          float w_ = wv[tt][k];
          if (w_ > 0.f) {
            float cbv = c[tt][k];
#pragma unroll
            for (int r = 0; r < R; r++) {
              float a = fminf(cmB[r], cbv);
              S[r][k] = fmaf(w_, a, S[r][k]);
              cbv = dl[r][k] + a;
            }
            c[tt][k] = cbv;
          }
        }
      }

      // ---- handoff ----
      if (wave < WVS - 1) {
        // intra-block: write slice + crow to LDS; consumer reads after next barrier
#pragma unroll
        for (int tt = 0; tt < BC; tt++) *(f4*)(lsl + tt * Nn) = c[tt];
        if ((lane >> 2) == j)
          *(f4*)&crow_lds[wave][j & (SLOTS - 1)][(lane & 3) * 4] = clast4;
      } else if (blk < NBLK - 1) {
        // wave 3: inter-block handoff via LLC (in-step publish, round-2 proven)
        if ((lane >> 2) == j) {
          float* cp = crowG + blk * Nn + 4 * lane;   // == blk*Nn + j*BC + (lane&3)*4
          asm volatile("global_store_dwordx4 %0, %1, off sc0 sc1" :: "v"(cp), "v"(clast4) : "memory");
        }
        llc_store_cbar16(cbarG + (size_t)j * BC * Nn + 4 * lane, c); // vmcnt(0) covers crow too
        if (lane == 0) llc_store_int(flags + blk * NCHUNK + j, 1);
      } else {
        // final stage: stash C_last into LDS for the fused reduction
        if ((lane >> 2) == j)
          *(f4*)&crow_fin[4 * lane] = clast4;
      }
    }
    __syncthreads();
  }

  // ---- fused final reduction (last block only): out = sum_n p_back[N][n] * C_last[n] ----
  if (blk == NBLK - 1) {
    float fw = p[tid] * q[Nn * Nn + tid] / (p[Nn] + EPSF);
    crow_fin[tid] *= fw;
    __syncthreads();
    for (int sft = 128; sft > 0; sft >>= 1) {
      if (tid < sft) crow_fin[tid] += crow_fin[tid + sft];
      __syncthreads();
    }
    if (tid == 0) out[0] = crow_fin[0];
  }
}

extern "C" void kernel_launch(void* const* d_in, const int* in_sizes, int n_in,
                              void* d_out, int out_size, void* d_ws, size_t ws_size,
                              hipStream_t stream) {
  const float* x = (const float*)d_in[0];
  const float* y = (const float*)d_in[1];
  const float* q = (const float*)d_in[2];
  float* ws = (float*)d_ws;
  float* out = (float*)d_out;
  hipLaunchKernelGGL(k_pre,   dim3(Mm + 257 + 1), dim3(256), 0, stream, x, y, q, ws);
  hipLaunchKernelGGL(k_reach, dim3(1),   dim3(256), 0, stream, ws + OFF_QC, ws + OFF_P);
  hipLaunchKernelGGL(k_wbuild,dim3(Nn),  dim3(256), 0, stream, ws + OFF_QC, ws + OFF_P,
                     ws + OFF_WT, ws + OFF_WS);
  hipLaunchKernelGGL(k_main,  dim3(NBLK), dim3(256), 0, stream, ws + OFF_D, ws + OFF_WT,
                     ws + OFF_WS, ws + OFF_CBAR, ws + OFF_CROW, (int*)(ws + OFF_FLAG),
                     q, ws + OFF_P, out);
}

// Round 12
// 466.653 us; speedup vs baseline: 1.7263x; 1.7263x over previous
//
#include <hip/hip_runtime.h>

typedef float f4 __attribute__((ext_vector_type(4)));

#define Nn 256
#define Mm 512
#define Dd 64
#define EPSF 1e-6f
#define INFF 1e30f
#define BC 8
#define NCHUNK (Nn / BC)   // 32
#define R 16               // rows per wave-stage
#define NBLK 8             // pipeline groups (blocks)
#define WVS 4              // waves per block (256 threads, 1 wave/SIMD)
#define SST (NBLK * WVS)   // 32 stages total
#define SLOTS 4            // LDS slice ring depth

// workspace layout (float offsets)
#define OFF_D     0                    // d[m][n]        512*256
#define OFF_QC    131072               // qc[nb][j]=q[j][nb]  256*257
#define OFF_P     (OFF_QC + 65792)     // p[257]
#define OFF_WT    (OFF_P + 260)        // wT[t][n]=w[n][t]    256*256
#define OFF_WS    (OFF_WT + 65536)     // (unused)
#define OFF_CBAR  (OFF_WS + 256)       // inter-block Cbar slices 256*256
#define OFF_CROW  (OFF_CBAR + 65536)   // C row handoffs (region sized SST*Nn)
#define OFF_FLAG  (OFF_CROW + SST*Nn)  // flags[blk][chunk], NBLK*NCHUNK ints

// ---------------- LLC-coherent (sc0 sc1) helpers — proven round-2 forms ----------------
__device__ __forceinline__ int llc_load_int(const int* p) {
  int v;
  asm volatile("global_load_dword %0, %1, off sc0 sc1\n\ts_waitcnt vmcnt(0)"
               : "=v"(v) : "v"(p) : "memory");
  return v;
}
__device__ __forceinline__ void llc_store_int(int* p, int v) {
  asm volatile("global_store_dword %0, %1, off sc0 sc1" :: "v"(p), "v"(v) : "memory");
}
// blocking: 8 cbar rows + 2 crow vectors in one round trip
__device__ __forceinline__ void llc_load_cbar10(const float* b0, const float* cp,
                                                f4 c[8], f4& pl, f4& ph) {
  const float* b1 = b0 + 4 * Nn;
  asm volatile(
    "global_load_dwordx4 %0, %10, off sc0 sc1\n\t"
    "global_load_dwordx4 %1, %10, off offset:1024 sc0 sc1\n\t"
    "global_load_dwordx4 %2, %10, off offset:2048 sc0 sc1\n\t"
    "global_load_dwordx4 %3, %10, off offset:3072 sc0 sc1\n\t"
    "global_load_dwordx4 %4, %11, off sc0 sc1\n\t"
    "global_load_dwordx4 %5, %11, off offset:1024 sc0 sc1\n\t"
    "global_load_dwordx4 %6, %11, off offset:2048 sc0 sc1\n\t"
    "global_load_dwordx4 %7, %11, off offset:3072 sc0 sc1\n\t"
    "global_load_dwordx4 %8, %12, off sc0 sc1\n\t"
    "global_load_dwordx4 %9, %12, off offset:16 sc0 sc1\n\t"
    "s_waitcnt vmcnt(0)"
    : "=v"(c[0]), "=v"(c[1]), "=v"(c[2]), "=v"(c[3]),
      "=v"(c[4]), "=v"(c[5]), "=v"(c[6]), "=v"(c[7]),
      "=v"(pl), "=v"(ph)
    : "v"(b0), "v"(b1), "v"(cp)
    : "memory");
}
__device__ __forceinline__ void llc_store_cbar8(float* b0, const f4 c[8]) {
  float* b1 = b0 + 4 * Nn;
  asm volatile(
    "global_store_dwordx4 %8, %0, off sc0 sc1\n\t"
    "global_store_dwordx4 %8, %1, off offset:1024 sc0 sc1\n\t"
    "global_store_dwordx4 %8, %2, off offset:2048 sc0 sc1\n\t"
    "global_store_dwordx4 %8, %3, off offset:3072 sc0 sc1\n\t"
    "global_store_dwordx4 %9, %4, off sc0 sc1\n\t"
    "global_store_dwordx4 %9, %5, off offset:1024 sc0 sc1\n\t"
    "global_store_dwordx4 %9, %6, off offset:2048 sc0 sc1\n\t"
    "global_store_dwordx4 %9, %7, off offset:3072 sc0 sc1\n\t"
    "s_waitcnt vmcnt(0)"
    :: "v"(c[0]), "v"(c[1]), "v"(c[2]), "v"(c[3]),
       "v"(c[4]), "v"(c[5]), "v"(c[6]), "v"(c[7]),
       "v"(b0), "v"(b1)
    : "memory");
}
__device__ __forceinline__ float rdlane(float v, int l) {
  return __int_as_float(__builtin_amdgcn_readlane(__float_as_int(v), l));
}

// ---------------- fused setup: dist (b<512) | qt (b<769) | init (b==769) ----------------
__global__ __launch_bounds__(256) void k_pre(const float* __restrict__ x,
                                             const float* __restrict__ y,
                                             const float* __restrict__ q,
                                             float* __restrict__ ws) {
  const int b = blockIdx.x, t = threadIdx.x;
  if (b < Mm) {
    __shared__ float xs[Dd];
    if (t < Dd) xs[t] = x[b * Dd + t];
    __syncthreads();
    const float4* y4 = (const float4*)(y + t * Dd);
    float acc = 0.f;
#pragma unroll
    for (int k = 0; k < Dd / 4; k++) {
      float4 v = y4[k];
      float a0 = xs[4*k+0] - v.x, a1 = xs[4*k+1] - v.y;
      float a2 = xs[4*k+2] - v.z, a3 = xs[4*k+3] - v.w;
      acc += a0*a0 + a1*a1 + a2*a2 + a3*a3;
    }
    ws[OFF_D + b * Nn + t] = sqrtf(acc);
  } else if (b < Mm + 257) {
    const int j = b - Mm;                 // qc[nb][j] = q[j][nb]
    ws[OFF_QC + t * 257 + j] = q[j * Nn + t];
  } else {
    ((int*)(ws + OFF_FLAG))[t] = 0;       // NBLK*NCHUNK == 256 flags
  }
}

// ---------------- reachability: sequential column accumulation, latency-fixed ----------------
// Reads q DIRECTLY (no qc): tile staging remapped so consecutive tid read consecutive columns
// (coalesced), and phase-2 uses per-thread contiguous float4 row segments (16 independent
// loads per group instead of 64+64 serialized scalar wave-loads).
__global__ __launch_bounds__(256) void k_reach(const float* __restrict__ q, float* __restrict__ p_out) {
  __shared__ float p[257];
  __shared__ float vsnap[64];
  __shared__ float qtile[64][65];
  int tid = threadIdx.x;
  p[tid] = (tid == 0) ? 1.f : 0.f;
  if (tid == 0) p[256] = 0.f;
  __syncthreads();
  for (int g = 0; g < 4; g++) {
    int g0 = g * 64;
    // qtile[k][l] = q[(g0+l)*Nn + g0+k]; consecutive tid -> consecutive k -> coalesced
    for (int z = 0; z < 16; z++) {
      int idx = tid + z * 256, l = idx >> 6, k = idx & 63;
      qtile[k][l] = q[(g0 + l) * Nn + g0 + k];
    }
    __syncthreads();
    if (tid < 64) {
      float pv = p[g0 + tid];
      for (int k = 0; k < 64; k++) {
        float v = __shfl(pv, k, 64);
        if (tid == k) vsnap[k] = v;
        pv += v * qtile[k][tid];
      }
    }
    __syncthreads();
    // phase 2: p[row] += sum_k vsnap[k] * q[row][g0+k], contiguous f4 row segment per thread
    float4 qs[16];
    const float4* qrow = (const float4*)(q + tid * Nn + g0);
#pragma unroll
    for (int i = 0; i < 16; i++) qs[i] = qrow[i];
    float acc = p[tid];
#pragma unroll
    for (int i = 0; i < 16; i++) {
      acc += vsnap[4*i+0] * qs[i].x;
      acc += vsnap[4*i+1] * qs[i].y;
      acc += vsnap[4*i+2] * qs[i].z;
      acc += vsnap[4*i+3] * qs[i].w;
    }
    float acc2 = 0.f;
    if (tid == 0) {
      acc2 = p[256];
      const float4* qlast = (const float4*)(q + 256 * Nn + g0);
#pragma unroll
      for (int i = 0; i < 16; i++) {
        float4 v = qlast[i];
        acc2 += vsnap[4*i+0] * v.x + vsnap[4*i+1] * v.y
              + vsnap[4*i+2] * v.z + vsnap[4*i+3] * v.w;
      }
    }
    __syncthreads();
    p[tid] = acc;
    if (tid == 0) p[256] = acc2;
    __syncthreads();
  }
  p_out[tid] = p[tid];
  if (tid == 0) p_out[256] = p[256];
}

// wT only — no atomic Wsum (k_main sums its own columns in a coalesced prologue)
__global__ __launch_bounds__(256) void k_wbuild(const float* __restrict__ qc, const float* __restrict__ p,
                                                float* __restrict__ wT) {
  int t = blockIdx.x, n = threadIdx.x;
  float v = 0.f;
  if (t < n) v = p[t] * qc[t * 257 + n] / (p[n] + EPSF);
  wT[t * Nn + n] = v;
}

// ---------------- main systolic DP: 8 blocks x 4 waves, round-2 proven protocol ----------------
__global__ __launch_bounds__(256, 1) void k_main(const float* __restrict__ d,
                                                 const float* __restrict__ wT,
                                                 float* __restrict__ cbarG,
                                                 float* __restrict__ crowG,
                                                 int* __restrict__ flags,
                                                 const float* __restrict__ q,
                                                 const float* __restrict__ p,
                                                 float* __restrict__ out) {
  __shared__ __align__(16) float sbuf[SLOTS][BC * Nn];       // 32 KB slice ring
  __shared__ __align__(16) float crow_lds[WVS][SLOTS][BC];   // crow handoffs
  __shared__ __align__(16) float crow_fin[Nn];               // last block: C_last stash

  const int tid  = threadIdx.x;
  const int wave = tid >> 6;         // 0..3: stage within block
  const int lane = tid & 63;         // owns columns 4*lane .. 4*lane+3
  const int blk  = blockIdx.x;
  const int stage = blk * WVS + wave;
  const int m0 = stage * R;

  f4 dl[R], S[R];
#pragma unroll
  for (int r = 0; r < R; r++) {
    dl[r] = *(const f4*)(d + (m0 + r) * Nn + 4 * lane);
    S[r] = (f4){0.f, 0.f, 0.f, 0.f};
  }
  // Wt prologue: column sums of wT (coalesced; replaces the atomic Wsum kernel)
  f4 Wt = (f4){0.f, 0.f, 0.f, 0.f};
#pragma unroll 8
  for (int t = 0; t < Nn; t++)
    Wt += *(const f4*)(wT + t * Nn + 4 * lane);

#pragma clang loop unroll(disable)
  for (int s = 0; s < NCHUNK + WVS - 1; s++) {
    const int j = s - wave;
    if (j >= 0 && j < NCHUNK) {
      // wT chunk: plain cached loads (read-only, L2-resident) — issue before any wait
      f4 wv[BC];
#pragma unroll
      for (int tt = 0; tt < BC; tt++)
        wv[tt] = *(const f4*)(wT + (j * BC + tt) * Nn + 4 * lane);

      f4 c[BC], cpl, cph;
      float* lsl = &sbuf[j & (SLOTS - 1)][0] + 4 * lane;

      if (wave == 0) {
        if (blk > 0) {
          const int* fp = flags + (blk - 1) * NCHUNK + j;
          while (llc_load_int(fp) == 0) __builtin_amdgcn_s_sleep(1);
          llc_load_cbar10(cbarG + (size_t)j * BC * Nn + 4 * lane,
                          crowG + (blk - 1) * Nn + j * BC, c, cpl, cph);
        } else {
          cpl = (f4){INFF, INFF, INFF, INFF};
          cph = cpl;
#pragma unroll
          for (int tt = 0; tt < BC; tt++) c[tt] = cpl;
        }
      } else {
        // slice written by wave-1 at step s-1 (barrier-separated)
#pragma unroll
        for (int tt = 0; tt < BC; tt++) c[tt] = *(const f4*)(lsl + tt * Nn);
        const float* cr = &crow_lds[wave - 1][j & (SLOTS - 1)][0];
        cpl = *(const f4*)cr;
        cph = *(const f4*)(cr + 4);
      }

      f4 clast4;
      const bool isJ0 = (j == 0);
#pragma unroll
      for (int tt = 0; tt < BC; tt++) {
        const int owner = 2 * j + (tt >> 2);   // wave-uniform
        const int comp = tt & 3;               // == t & 3 (compile-time)
        const bool isT0 = isJ0 && (tt == 0);

        float up = (tt < 4) ? cpl[comp] : cph[comp];   // upstream C[m0-1][t]
        float prcMin = up;                              // for cmin2
        float prcVal = up;                              // for the t==0 value chain
        if (isT0 && stage == 0) prcVal = 0.f;
        float cml[R];
#pragma unroll
        for (int r = 0; r < R; r++) {
          float Cv;
          if (isT0) Cv = dl[r][0] + prcVal;                       // C[m][0] = d + C[m-1][0]
          else      Cv = fmaf(dl[r][comp], Wt[comp], S[r][comp]); // C[m][t] = d*W + S
          cml[r] = fminf(Cv, prcMin);                             // cmin2 = min(C[m][t], C[m-1][t])
          prcVal = Cv;
          prcMin = Cv;
        }
        // broadcast owner lane's cmin2 chain + last-row C to all lanes
        float cmB[R];
#pragma unroll
        for (int r = 0; r < R; r++) cmB[r] = rdlane(cml[r], owner);
        float clastv = rdlane(prcVal, owner);
        if (lane == owner) clast4[comp] = clastv;

        // stream update: for each owned column n, chain Cbar through 16 rows
#pragma unroll
        for (int k = 0; k < 4; k++) {
          float w_ = wv[tt][k];
          if (w_ > 0.f) {
            float cbv = c[tt][k];
#pragma unroll
            for (int r = 0; r < R; r++) {
              float a = fminf(cmB[r], cbv);
              S[r][k] = fmaf(w_, a, S[r][k]);
              cbv = dl[r][k] + a;
            }
            c[tt][k] = cbv;
          }
        }
      }

      // ---- handoff ----
      if (wave < WVS - 1) {
        // intra-block: write slice + crow to LDS; consumer reads after next barrier
#pragma unroll
        for (int tt = 0; tt < BC; tt++) *(f4*)(lsl + tt * Nn) = c[tt];
        if (lane == 2 * j || lane == 2 * j + 1)
          *(f4*)&crow_lds[wave][j & (SLOTS - 1)][(lane & 1) * 4] = clast4;
      } else if (blk < NBLK - 1) {
        // wave 3: inter-block handoff via LLC (in-step publish, round-2 proven)
        if (lane == 2 * j || lane == 2 * j + 1) {
          float* cp = crowG + blk * Nn + j * BC + (lane & 1) * 4;
          asm volatile("global_store_dwordx4 %0, %1, off sc0 sc1" :: "v"(cp), "v"(clast4) : "memory");
        }
        llc_store_cbar8(cbarG + (size_t)j * BC * Nn + 4 * lane, c); // vmcnt(0) covers crow too
        if (lane == 0) llc_store_int(flags + blk * NCHUNK + j, 1);
      } else {
        // final stage: stash C_last into LDS for the fused reduction
        if (lane == 2 * j || lane == 2 * j + 1)
          *(f4*)&crow_fin[j * BC + (lane & 1) * 4] = clast4;
      }
    }
    __syncthreads();
  }

  // ---- fused final reduction (last block only): out = sum_n p_back[N][n] * C_last[n] ----
  if (blk == NBLK - 1) {
    float fw = p[tid] * q[Nn * Nn + tid] / (p[Nn] + EPSF);
    crow_fin[tid] *= fw;
    __syncthreads();
    for (int sft = 128; sft > 0; sft >>= 1) {
      if (tid < sft) crow_fin[tid] += crow_fin[tid + sft];
      __syncthreads();
    }
    if (tid == 0) out[0] = crow_fin[0];
  }
}

extern "C" void kernel_launch(void* const* d_in, const int* in_sizes, int n_in,
                              void* d_out, int out_size, void* d_ws, size_t ws_size,
                              hipStream_t stream) {
  const float* x = (const float*)d_in[0];
  const float* y = (const float*)d_in[1];
  const float* q = (const float*)d_in[2];
  float* ws = (float*)d_ws;
  float* out = (float*)d_out;
  hipLaunchKernelGGL(k_pre,   dim3(Mm + 257 + 1), dim3(256), 0, stream, x, y, q, ws);
  hipLaunchKernelGGL(k_reach, dim3(1),   dim3(256), 0, stream, q, ws + OFF_P);
  hipLaunchKernelGGL(k_wbuild,dim3(Nn),  dim3(256), 0, stream, ws + OFF_QC, ws + OFF_P,
                     ws + OFF_WT);
  hipLaunchKernelGGL(k_main,  dim3(NBLK), dim3(256), 0, stream, ws + OFF_D, ws + OFF_WT,
                     ws + OFF_CBAR, ws + OFF_CROW, (int*)(ws + OFF_FLAG),
                     q, ws + OFF_P, out);
}